// Round 3
// baseline (41.980 us; speedup 1.0000x reference)
//
#include <hip/hip_runtime.h>
#include <math.h>

// Poisson MC estimator. R3: landmark constants moved from LDS broadcasts to
// the SCALAR memory pipe (s_load_dwordx16 from a packed d_ws buffer).
// R1/R2 evidence: 4096 broadcast ds_read_b128 per CU (~12cy each ~ 20us on
// the shared LDS pipe) bounded both rounds (~same time despite 2x occupancy).
// SGPR-resident landmark data feeds VALU directly (1 SGPR/instr - legal),
// freeing the LDS pipe entirely; VALU issue becomes the limiter (~10-11us).

#define EPS2    1e-4f
#define INV_4PI 0.07957747154594767f

constexpr int M_LAND = 2048;
constexpr int NW     = 16;                 // waves per block
constexpr int SLICE  = M_LAND / NW;        // 128 landmarks per wave
constexpr int QPB    = 128;                // queries per block
constexpr int NGRP   = SLICE / 2;          // 64 groups of 2 landmarks (64B)

typedef float f32x16 __attribute__((ext_vector_type(16)));

// ---- pack kernel: ws[8j..] = (-2y0,-2y1,-2y2, ||y||^2+eps^2, -2gy0,-2gy1,-2gy2, g)
__global__ void poisson_pack_kernel(const float* __restrict__ xl,
                                    const float* __restrict__ gl,
                                    float* __restrict__ ws)
{
    int j = blockIdx.x * 256 + threadIdx.x;
    if (j < M_LAND) {
        float l0 = xl[3*j], l1 = xl[3*j+1], l2 = xl[3*j+2], g = gl[j];
        float n2 = l0*l0 + l1*l1 + l2*l2 + EPS2;
        float* r = ws + 8*j;
        r[0] = -2.0f*l0;   r[1] = -2.0f*l1;   r[2] = -2.0f*l2;   r[3] = n2;
        r[4] = -2.0f*g*l0; r[5] = -2.0f*g*l1; r[6] = -2.0f*g*l2; r[7] = g;
    }
}

// issue one 64B scalar load (2 landmarks) — no wait
#define LOAD1(D, P) \
    asm volatile("s_load_dwordx16 %0, %1, 0x0" : "=&s"(D) : "s"(P))

// drain SMEM + fence the scheduler (rule #18: reg-only ops can be hoisted
// past an inline-asm waitcnt unless followed by sched_barrier(0))
#define SWAIT() do { \
    asm volatile("s_waitcnt lgkmcnt(0)" ::: "memory"); \
    __builtin_amdgcn_sched_barrier(0); \
} while (0)

// one landmark (SGPR constants) x two queries (VGPR state): 24 VALU + 2 rsq
#define LM(PX,PY,PZ,PW,GX,GY,GZ,GG) do { \
    float ta = fmaf((PX), a0, fmaf((PY), a1, fmaf((PZ), a2, qea))) + (PW); \
    ta = fmaxf(ta, EPS2); \
    float sa  = __builtin_amdgcn_rsqf(ta); \
    float s3a = sa * sa * sa; \
    av_a = fmaf((GG), sa,  av_a);  ac_a = fmaf((GG), s3a, ac_a); \
    ax_a = fmaf(s3a, (GX), ax_a);  ay_a = fmaf(s3a, (GY), ay_a); \
    az_a = fmaf(s3a, (GZ), az_a); \
    float tb = fmaf((PX), b0, fmaf((PY), b1, fmaf((PZ), b2, qeb))) + (PW); \
    tb = fmaxf(tb, EPS2); \
    float sb  = __builtin_amdgcn_rsqf(tb); \
    float s3b = sb * sb * sb; \
    av_b = fmaf((GG), sb,  av_b);  ac_b = fmaf((GG), s3b, ac_b); \
    ax_b = fmaf(s3b, (GX), ax_b);  ay_b = fmaf(s3b, (GY), ay_b); \
    az_b = fmaf(s3b, (GZ), az_b); \
} while (0)

#define COMP2(D) do { \
    LM(D[0],D[1],D[2],D[3],D[4],D[5],D[6],D[7]); \
    LM(D[8],D[9],D[10],D[11],D[12],D[13],D[14],D[15]); \
} while (0)

__global__ __launch_bounds__(1024, 4)
void poisson_smem_kernel(const float* __restrict__ xq,
                         const float* __restrict__ ws,
                         float* __restrict__ out, int B)
{
    __shared__ float part[NW][QPB][5];     // 40 KB

    const int tid   = threadIdx.x;
    const int lane  = tid & 63;
    const int w     = tid >> 6;
    const int qbase = blockIdx.x * QPB;
    const int qa    = qbase + lane;
    const int qb    = qbase + 64 + lane;

    const float a0 = xq[3*qa], a1 = xq[3*qa+1], a2 = xq[3*qa+2];
    const float b0 = xq[3*qb], b1 = xq[3*qb+1], b2 = xq[3*qb+2];
    const float qea = a0*a0 + a1*a1 + a2*a2;
    const float qeb = b0*b0 + b1*b1 + b2*b2;

    float av_a=0.f, ac_a=0.f, ax_a=0.f, ay_a=0.f, az_a=0.f;
    float av_b=0.f, ac_b=0.f, ax_b=0.f, ay_b=0.f, az_b=0.f;

    // uniform-by-construction wave base (keeps all address math scalar)
    const int wu = __builtin_amdgcn_readfirstlane(w * SLICE);
    const float* base = ws + (size_t)wu * 8;

    f32x16 A, Bv;
    LOAD1(A, base);
    SWAIT();

#pragma unroll 1
    for (int g = 0; g + 2 < NGRP; g += 2) {
        LOAD1(Bv, base + (g + 1) * 16);    // prefetch next group
        COMP2(A);                          // ~104 cy of VALU hides it
        SWAIT();
        LOAD1(A, base + (g + 2) * 16);
        COMP2(Bv);
        SWAIT();
    }
    // g == NGRP-2: A holds group 62
    LOAD1(Bv, base + (NGRP - 1) * 16);
    COMP2(A);
    SWAIT();
    COMP2(Bv);

    // ---- per-(wave, query) partials ----
    part[w][lane][0] = av_a;  part[w][lane][1] = ac_a;
    part[w][lane][2] = ax_a;  part[w][lane][3] = ay_a;  part[w][lane][4] = az_a;
    part[w][lane+64][0] = av_b;  part[w][lane+64][1] = ac_b;
    part[w][lane+64][2] = ax_b;  part[w][lane+64][3] = ay_b;  part[w][lane+64][4] = az_b;

    __syncthreads();

    if (tid < 512) {
        const int q   = tid >> 2;
        const int cmp = tid & 3;
        const int qg  = qbase + q;
        if (cmp == 0) {
            float s = 0.f;
            #pragma unroll
            for (int ww = 0; ww < NW; ++ww) s += part[ww][q][0];
            out[qg] = s * (INV_4PI / (float)M_LAND);
        } else {
            float sc = 0.f, sy = 0.f;
            #pragma unroll
            for (int ww = 0; ww < NW; ++ww) {
                sc += part[ww][q][1];
                sy += part[ww][q][1 + cmp];
            }
            const float qc = xq[3*qg + (cmp-1)];
            out[B + 3*qg + (cmp-1)] =
                (-INV_4PI / (float)M_LAND) * fmaf(qc, sc, 0.5f * sy);
        }
    }
}

// ---------------- fallback (R2 kernel) if ws_size is too small ----------------
__global__ __launch_bounds__(1024, 4)
void poisson_lds_kernel(const float* __restrict__ xq,
                        const float* __restrict__ xl,
                        const float* __restrict__ gl,
                        float* __restrict__ out, int B)
{
    __shared__ float4 pack[M_LAND];
    __shared__ float4 gpack[M_LAND];
    __shared__ float  part[NW][QPB][5];

    const int tid = threadIdx.x;
    for (int j = tid; j < M_LAND; j += 1024) {
        float l0 = xl[3*j], l1 = xl[3*j+1], l2 = xl[3*j+2], g = gl[j];
        float n2 = l0*l0 + l1*l1 + l2*l2 + EPS2;
        pack[j]  = make_float4(-2.0f*l0, -2.0f*l1, -2.0f*l2, n2);
        gpack[j] = make_float4(-2.0f*g*l0, -2.0f*g*l1, -2.0f*g*l2, g);
    }
    const int lane = tid & 63, w = tid >> 6;
    const int qbase = blockIdx.x * QPB;
    const int qa = qbase + lane, qb = qbase + 64 + lane;
    const float a0 = xq[3*qa], a1 = xq[3*qa+1], a2 = xq[3*qa+2];
    const float b0 = xq[3*qb], b1 = xq[3*qb+1], b2 = xq[3*qb+2];
    const float qea = a0*a0 + a1*a1 + a2*a2;
    const float qeb = b0*b0 + b1*b1 + b2*b2;
    __syncthreads();

    float av_a=0.f, ac_a=0.f, ax_a=0.f, ay_a=0.f, az_a=0.f;
    float av_b=0.f, ac_b=0.f, ax_b=0.f, ay_b=0.f, az_b=0.f;
    const int base = w * SLICE;
#pragma unroll 8
    for (int i = 0; i < SLICE; ++i) {
        const float4 p  = pack[base + i];
        const float4 gp = gpack[base + i];
        float ta = fmaf(p.x, a0, fmaf(p.y, a1, fmaf(p.z, a2, qea))) + p.w;
        ta = fmaxf(ta, EPS2);
        float sa = __builtin_amdgcn_rsqf(ta);
        float s3a = sa*sa*sa;
        av_a = fmaf(gp.w, sa, av_a);  ac_a = fmaf(gp.w, s3a, ac_a);
        ax_a = fmaf(s3a, gp.x, ax_a); ay_a = fmaf(s3a, gp.y, ay_a);
        az_a = fmaf(s3a, gp.z, az_a);
        float tb = fmaf(p.x, b0, fmaf(p.y, b1, fmaf(p.z, b2, qeb))) + p.w;
        tb = fmaxf(tb, EPS2);
        float sb = __builtin_amdgcn_rsqf(tb);
        float s3b = sb*sb*sb;
        av_b = fmaf(gp.w, sb, av_b);  ac_b = fmaf(gp.w, s3b, ac_b);
        ax_b = fmaf(s3b, gp.x, ax_b); ay_b = fmaf(s3b, gp.y, ay_b);
        az_b = fmaf(s3b, gp.z, az_b);
    }
    part[w][lane][0] = av_a;  part[w][lane][1] = ac_a;
    part[w][lane][2] = ax_a;  part[w][lane][3] = ay_a;  part[w][lane][4] = az_a;
    part[w][lane+64][0] = av_b;  part[w][lane+64][1] = ac_b;
    part[w][lane+64][2] = ax_b;  part[w][lane+64][3] = ay_b;  part[w][lane+64][4] = az_b;
    __syncthreads();
    if (tid < 512) {
        const int q = tid >> 2, cmp = tid & 3, qg = qbase + q;
        if (cmp == 0) {
            float s = 0.f;
            #pragma unroll
            for (int ww = 0; ww < NW; ++ww) s += part[ww][q][0];
            out[qg] = s * (INV_4PI / (float)M_LAND);
        } else {
            float sc = 0.f, sy = 0.f;
            #pragma unroll
            for (int ww = 0; ww < NW; ++ww) {
                sc += part[ww][q][1];
                sy += part[ww][q][1 + cmp];
            }
            const float qc = xq[3*qg + (cmp-1)];
            out[B + 3*qg + (cmp-1)] =
                (-INV_4PI / (float)M_LAND) * fmaf(qc, sc, 0.5f * sy);
        }
    }
}

extern "C" void kernel_launch(void* const* d_in, const int* in_sizes, int n_in,
                              void* d_out, int out_size, void* d_ws, size_t ws_size,
                              hipStream_t stream)
{
    const float* xq = (const float*)d_in[0];   // (B,3)
    const float* xl = (const float*)d_in[1];   // (M,3)
    const float* gl = (const float*)d_in[2];   // (M,)
    float* out = (float*)d_out;

    const int B    = in_sizes[0] / 3;          // 32768
    const int grid = B / QPB;                  // 256

    if (ws_size >= (size_t)(M_LAND * 8 * sizeof(float))) {
        float* ws = (float*)d_ws;
        poisson_pack_kernel<<<(M_LAND + 255) / 256, 256, 0, stream>>>(xl, gl, ws);
        poisson_smem_kernel<<<grid, 1024, 0, stream>>>(xq, ws, out, B);
    } else {
        poisson_lds_kernel<<<grid, 1024, 0, stream>>>(xq, xl, gl, out, B);
    }
}

// Round 4
// 26.909 us; speedup vs baseline: 1.5601x; 1.5601x over previous
//
#include <hip/hip_runtime.h>
#include <math.h>

// Poisson MC estimator. R4 = R2 structure (LDS broadcast of landmark packs,
// known-good) + packed-fp32 VOP3P math: the two queries per lane ride lo/hi
// of VGPR pairs; wave-uniform landmark constants broadcast into both halves
// via op_sel/op_sel_hi. Cuts per-landmark VALU issue from ~64cy to ~42cy.
// Asm blocks are NON-volatile pure computation -> compiler may pipeline
// across iterations (R3's volatile+sched_barrier serialization regressed).

#define EPS2    1e-4f
#define INV_4PI 0.07957747154594767f

constexpr int M_LAND = 2048;
constexpr int NW     = 16;                 // waves per block
constexpr int SLICE  = M_LAND / NW;        // 128 landmarks per wave
constexpr int QPB    = 128;                // queries per block (64 lanes x 2)

typedef float f32x2 __attribute__((ext_vector_type(2)));

__global__ __launch_bounds__(1024, 4)
void poisson_pk_kernel(const float* __restrict__ xq,
                       const float* __restrict__ xl,
                       const float* __restrict__ gl,
                       float* __restrict__ out, int B)
{
    __shared__ float4 pack[M_LAND];        // (-2y0,-2y1,-2y2, ||y||^2+eps^2)
    __shared__ float4 gpack[M_LAND];       // (-2gy0,-2gy1,-2gy2, g)
    __shared__ float  part[NW][QPB][5];

    const int tid = threadIdx.x;

    for (int j = tid; j < M_LAND; j += 1024) {
        float l0 = xl[3*j], l1 = xl[3*j+1], l2 = xl[3*j+2], g = gl[j];
        float n2 = l0*l0 + l1*l1 + l2*l2 + EPS2;
        pack[j]  = make_float4(-2.0f*l0, -2.0f*l1, -2.0f*l2, n2);
        gpack[j] = make_float4(-2.0f*g*l0, -2.0f*g*l1, -2.0f*g*l2, g);
    }

    const int lane  = tid & 63;
    const int w     = tid >> 6;
    const int qbase = blockIdx.x * QPB;
    const int qa    = qbase + lane;
    const int qb    = qbase + 64 + lane;

    const float a0 = xq[3*qa], a1 = xq[3*qa+1], a2 = xq[3*qa+2];
    const float b0 = xq[3*qb], b1 = xq[3*qb+1], b2 = xq[3*qb+2];

    // lo half = query A, hi half = query B
    f32x2 Q0 = {a0, b0}, Q1 = {a1, b1}, Q2 = {a2, b2};
    f32x2 QE = {a0*a0 + a1*a1 + a2*a2, b0*b0 + b1*b1 + b2*b2};
    f32x2 AV = {0.f,0.f}, AC = {0.f,0.f}, AX = {0.f,0.f}, AY = {0.f,0.f}, AZ = {0.f,0.f};

    __syncthreads();

    const int base = w * SLICE;
#pragma unroll 8
    for (int i = 0; i < SLICE; ++i) {
        const float4 p  = pack[base + i];   // broadcast ds_read_b128
        const float4 gp = gpack[base + i];  // broadcast ds_read_b128
        f32x2 P01 = {p.x,  p.y};            // (px, py)   sub-pair of b128 dest
        f32x2 P2W = {p.z,  p.w};            // (pz, pw)
        f32x2 G01 = {gp.x, gp.y};           // (gx, gy)
        f32x2 G2G = {gp.z, gp.w};           // (gz, gg)

        // T = (QE + pw) + pz*Q2 + py*Q1 + px*Q0   (both halves; landmark
        // scalars broadcast from pair halves via op_sel/op_sel_hi)
        f32x2 T;
        asm("v_pk_add_f32 %0, %1, %2 op_sel:[0,1] op_sel_hi:[1,1]\n\t"
            "v_pk_fma_f32 %0, %2, %3, %0 op_sel:[0,0,0] op_sel_hi:[0,1,1]\n\t"
            "v_pk_fma_f32 %0, %4, %5, %0 op_sel:[1,0,0] op_sel_hi:[1,1,1]\n\t"
            "v_pk_fma_f32 %0, %4, %6, %0 op_sel:[0,0,0] op_sel_hi:[0,1,1]"
            : "=&v"(T)
            : "v"(QE), "v"(P2W), "v"(Q2), "v"(P01), "v"(Q1), "v"(Q0));

        float ta = fmaxf(T.x, EPS2);        // == maximum(r2,0)+eps^2 exactly
        float tb = fmaxf(T.y, EPS2);
        f32x2 S = { __builtin_amdgcn_rsqf(ta), __builtin_amdgcn_rsqf(tb) };

        // S2=S*S; S3=S2*S; AV+=gg*S; AC+=gg*S3; AX+=S3*gx; AY+=S3*gy; AZ+=S3*gz
        f32x2 S2, S3;
        asm("v_pk_mul_f32 %0, %7, %7 op_sel:[0,0] op_sel_hi:[1,1]\n\t"
            "v_pk_mul_f32 %1, %0, %7 op_sel:[0,0] op_sel_hi:[1,1]\n\t"
            "v_pk_fma_f32 %2, %8, %7, %2 op_sel:[1,0,0] op_sel_hi:[1,1,1]\n\t"
            "v_pk_fma_f32 %3, %8, %1, %3 op_sel:[1,0,0] op_sel_hi:[1,1,1]\n\t"
            "v_pk_fma_f32 %4, %1, %9, %4 op_sel:[0,0,0] op_sel_hi:[1,0,1]\n\t"
            "v_pk_fma_f32 %5, %1, %9, %5 op_sel:[0,1,0] op_sel_hi:[1,1,1]\n\t"
            "v_pk_fma_f32 %6, %1, %8, %6 op_sel:[0,0,0] op_sel_hi:[1,0,1]"
            : "=&v"(S2), "=&v"(S3),
              "+v"(AV), "+v"(AC), "+v"(AX), "+v"(AY), "+v"(AZ)
            : "v"(S), "v"(G2G), "v"(G01));
    }

    // ---- per-(wave, query) partials ----
    part[w][lane][0] = AV.x;  part[w][lane][1] = AC.x;
    part[w][lane][2] = AX.x;  part[w][lane][3] = AY.x;  part[w][lane][4] = AZ.x;
    part[w][lane+64][0] = AV.y;  part[w][lane+64][1] = AC.y;
    part[w][lane+64][2] = AX.y;  part[w][lane+64][3] = AY.y;  part[w][lane+64][4] = AZ.y;

    __syncthreads();

    if (tid < 512) {
        const int q   = tid >> 2;
        const int cmp = tid & 3;
        const int qg  = qbase + q;
        if (cmp == 0) {
            float s = 0.f;
            #pragma unroll
            for (int ww = 0; ww < NW; ++ww) s += part[ww][q][0];
            out[qg] = s * (INV_4PI / (float)M_LAND);
        } else {
            float sc = 0.f, sy = 0.f;
            #pragma unroll
            for (int ww = 0; ww < NW; ++ww) {
                sc += part[ww][q][1];
                sy += part[ww][q][1 + cmp];    // Σ c*(-2 y_c)
            }
            const float qc = xq[3*qg + (cmp-1)];
            // grad_c = -inv4pi/M * (q_c*Σc + sy/2)
            out[B + 3*qg + (cmp-1)] =
                (-INV_4PI / (float)M_LAND) * fmaf(qc, sc, 0.5f * sy);
        }
    }
}

extern "C" void kernel_launch(void* const* d_in, const int* in_sizes, int n_in,
                              void* d_out, int out_size, void* d_ws, size_t ws_size,
                              hipStream_t stream)
{
    const float* xq = (const float*)d_in[0];   // (B,3)
    const float* xl = (const float*)d_in[1];   // (M,3)
    const float* gl = (const float*)d_in[2];   // (M,)
    float* out = (float*)d_out;

    const int B    = in_sizes[0] / 3;          // 32768
    const int grid = B / QPB;                  // 256 blocks (1 per CU)

    poisson_pk_kernel<<<grid, 1024, 0, stream>>>(xq, xl, gl, out, B);
}